// Round 3
// baseline (14117.644 us; speedup 1.0000x reference)
//
#include <hip/hip_runtime.h>

// voltageNN: 2-layer LSTM (H=256, proj P=1, in=1) over T=1000, B=16384, + MLP head.
// One wave (64 lanes) per batch element; lane owns hidden units u = lane + 64k, k=0..3,
// for BOTH layers. All fp32. Activations via prescaled exp2 + v_rcp (1-ulp class).

#define T_LEN 1000
#define WAVES 4
#define L2E 1.44269504088896340736f

static __device__ __forceinline__ float rcp_fast(float x) {
    return __builtin_amdgcn_rcpf(x);
}
// y = -L2E * z  ->  sigmoid(z) = 1/(1+2^y)
static __device__ __forceinline__ float sig_y(float y) {
    return rcp_fast(1.0f + exp2f(y));
}
// y = 2*L2E * z ->  tanh(z) = 1 - 2/(2^y + 1)
static __device__ __forceinline__ float tanh_y(float y) {
    return fmaf(-2.0f, rcp_fast(exp2f(y) + 1.0f), 1.0f);
}

struct CellW {
    float wi[4], wf[4], wg[4], wo[4];   // input weights (prescaled)
    float vi[4], vf[4], vg[4], vo[4];   // recurrent weights (prescaled)
    float bi[4], bf[4], bg[4], bo[4];   // biases (bih+bhh, prescaled)
    float wr[4];                        // projection row
};

static __device__ __forceinline__ void load_w(CellW& W, int lane,
        const float* __restrict__ Wih, const float* __restrict__ Whh,
        const float* __restrict__ bih, const float* __restrict__ bhh,
        const float* __restrict__ Whr) {
#pragma unroll
    for (int k = 0; k < 4; ++k) {
        int u = lane + 64 * k;
        W.wi[k] = -L2E * Wih[u];
        W.wf[k] = -L2E * Wih[256 + u];
        W.wg[k] = 2.0f * L2E * Wih[512 + u];
        W.wo[k] = -L2E * Wih[768 + u];
        W.vi[k] = -L2E * Whh[u];
        W.vf[k] = -L2E * Whh[256 + u];
        W.vg[k] = 2.0f * L2E * Whh[512 + u];
        W.vo[k] = -L2E * Whh[768 + u];
        W.bi[k] = -L2E * (bih[u] + bhh[u]);
        W.bf[k] = -L2E * (bih[256 + u] + bhh[256 + u]);
        W.bg[k] = 2.0f * L2E * (bih[512 + u] + bhh[512 + u]);
        W.bo[k] = -L2E * (bih[768 + u] + bhh[768 + u]);
        W.wr[k] = Whr[u];
    }
}

// One LSTM cell step for this lane's 4 hidden units; returns the lane-partial
// of the projection dot (needs wave-reduction afterwards). Updates c[] in place.
static __device__ __forceinline__ float cell_partial(const CellW& W, float xin,
                                                     float hrec, float (&c)[4]) {
    float s = 0.0f;
#pragma unroll
    for (int k = 0; k < 4; ++k) {
        float yi = fmaf(xin, W.wi[k], fmaf(hrec, W.vi[k], W.bi[k]));
        float yf = fmaf(xin, W.wf[k], fmaf(hrec, W.vf[k], W.bf[k]));
        float yg = fmaf(xin, W.wg[k], fmaf(hrec, W.vg[k], W.bg[k]));
        float yo = fmaf(xin, W.wo[k], fmaf(hrec, W.vo[k], W.bo[k]));
        float ig = sig_y(yi);
        float fg = sig_y(yf);
        float gg = tanh_y(yg);
        float og = sig_y(yo);
        float cn = fmaf(fg, c[k], ig * gg);
        c[k] = cn;
        float tc = tanh_y(cn * (2.0f * L2E));
        s = fmaf(og * tc, W.wr[k], s);
    }
    return s;
}

__global__ __launch_bounds__(256, 3)
void voltage_lstm_kernel(const float* __restrict__ x,
        const float* __restrict__ Wih0, const float* __restrict__ Whh0,
        const float* __restrict__ bih0, const float* __restrict__ bhh0,
        const float* __restrict__ Whr0,
        const float* __restrict__ Wih1, const float* __restrict__ Whh1,
        const float* __restrict__ bih1, const float* __restrict__ bhh1,
        const float* __restrict__ Whr1,
        const float* __restrict__ W1, const float* __restrict__ b1,
        const float* __restrict__ W2, const float* __restrict__ b2,
        float* __restrict__ out)
{
    __shared__ __align__(16) float h1buf[WAVES][T_LEN];

    const int lane = threadIdx.x & 63;
    const int wv   = threadIdx.x >> 6;
    const int b    = blockIdx.x * WAVES + wv;

    CellW W0c, W1c;
    load_w(W0c, lane, Wih0, Whh0, bih0, bhh0, Whr0);
    load_w(W1c, lane, Wih1, Whh1, bih1, bhh1, Whr1);

    float c0[4] = {0.f, 0.f, 0.f, 0.f};
    float c1[4] = {0.f, 0.f, 0.f, 0.f};

    const float* xb = x + (long)b * T_LEN;

    // --- prologue: layer0 step 0 (h0_init = 0) ---
    float xchunk = xb[lane];                 // chunk for t in [0,64)
    float xt = __shfl(xchunk, 0, 64);
    float s0 = cell_partial(W0c, xt, 0.0f, c0);
#pragma unroll
    for (int m = 1; m < 64; m <<= 1) s0 += __shfl_xor(s0, m, 64);
    float h0 = s0;      // layer0 output at t=0
    float h1v = 0.0f;   // layer1 recurrent state

    // --- main loop: iteration j computes layer1 step j AND layer0 step j+1.
    // Both depend only on h0_j -> independent -> interleave for ILP.
    for (int j = 0; j < T_LEN - 1; ++j) {
        const int idx = j + 1;               // layer0 time index
        if ((idx & 63) == 0) {
            int tl = idx + lane;
            xchunk = (tl < T_LEN) ? xb[tl] : 0.0f;
        }
        xt = __shfl(xchunk, idx & 63, 64);

        float a0 = cell_partial(W0c, xt, h0, c0);   // layer0, step idx
        float a1 = cell_partial(W1c, h0, h1v, c1);  // layer1, step j
#pragma unroll
        for (int m = 1; m < 64; m <<= 1) {
            a0 += __shfl_xor(a0, m, 64);
            a1 += __shfl_xor(a1, m, 64);
        }
        if (lane == 0) h1buf[wv][j] = a1;
        h0 = a0;
        h1v = a1;
    }
    // --- epilogue: layer1 step T-1 ---
    {
        float a1 = cell_partial(W1c, h0, h1v, c1);
#pragma unroll
        for (int m = 1; m < 64; m <<= 1) a1 += __shfl_xor(a1, m, 64);
        if (lane == 0) h1buf[wv][T_LEN - 1] = a1;
    }
    __syncthreads();

    // --- head: out1[j] = relu(b1[j] + sum_t W1[j,t]*h1[t]); out = b2 + sum_j W2[j]*out1[j]
    const float* hp = h1buf[wv];
    const int j0 = lane;                    // rows 0..63
    const int j1r = lane + 64;              // rows 64..99 (lanes 0..35)
    const bool has1 = (j1r < 100);
    const float* r0 = W1 + j0 * T_LEN;
    const float* r1 = W1 + (has1 ? j1r : 0) * T_LEN;
    float a0 = 0.0f, a1 = 0.0f;
    for (int t = 0; t < T_LEN; t += 4) {
        float4 hv = *(const float4*)(hp + t);      // broadcast LDS read
        float4 u0 = *(const float4*)(r0 + t);
        float4 u1 = *(const float4*)(r1 + t);
        a0 = fmaf(u0.x, hv.x, a0); a0 = fmaf(u0.y, hv.y, a0);
        a0 = fmaf(u0.z, hv.z, a0); a0 = fmaf(u0.w, hv.w, a0);
        a1 = fmaf(u1.x, hv.x, a1); a1 = fmaf(u1.y, hv.y, a1);
        a1 = fmaf(u1.z, hv.z, a1); a1 = fmaf(u1.w, hv.w, a1);
    }
    float p0 = fmaxf(a0 + b1[j0], 0.0f) * W2[j0];
    float p1 = has1 ? (fmaxf(a1 + b1[j1r], 0.0f) * W2[j1r]) : 0.0f;
    float s = p0 + p1;
#pragma unroll
    for (int m = 1; m < 64; m <<= 1) s += __shfl_xor(s, m, 64);
    if (lane == 0) out[b] = s + b2[0];
}

extern "C" void kernel_launch(void* const* d_in, const int* in_sizes, int n_in,
                              void* d_out, int out_size, void* d_ws, size_t ws_size,
                              hipStream_t stream) {
    (void)in_sizes; (void)n_in; (void)d_ws; (void)ws_size; (void)out_size;
    const float* x    = (const float*)d_in[0];
    const float* Wih0 = (const float*)d_in[1];
    const float* Whh0 = (const float*)d_in[2];
    const float* bih0 = (const float*)d_in[3];
    const float* bhh0 = (const float*)d_in[4];
    const float* Whr0 = (const float*)d_in[5];
    const float* Wih1 = (const float*)d_in[6];
    const float* Whh1 = (const float*)d_in[7];
    const float* bih1 = (const float*)d_in[8];
    const float* bhh1 = (const float*)d_in[9];
    const float* Whr1 = (const float*)d_in[10];
    const float* W1   = (const float*)d_in[11];
    const float* b1   = (const float*)d_in[12];
    const float* W2   = (const float*)d_in[13];
    const float* b2   = (const float*)d_in[14];
    float* outp = (float*)d_out;

    dim3 grid(16384 / WAVES), block(256);
    voltage_lstm_kernel<<<grid, block, 0, stream>>>(
        x, Wih0, Whh0, bih0, bhh0, Whr0,
        Wih1, Whh1, bih1, bhh1, Whr1,
        W1, b1, W2, b2, outp);
}

// Round 4
// 8481.574 us; speedup vs baseline: 1.6645x; 1.6645x over previous
//
#include <hip/hip_runtime.h>

// voltageNN: 2-layer LSTM (H=256, P=1, in=1), T=1000, B=16384, + MLP head.
// One wave per 2 batch elements; lane owns hidden units u = lane + 64k (k=0..3)
// for both layers. Recurrent scalars h0/h1 live in SGPRs (readlane), cross-lane
// reduction via DPP shr-tree (no LDS). Activations: prescaled exp2 + rcp with
// fused sigmoid*tanh products (8 trans/unit-step).

#define T_LEN 1000
#define WAVES 4     // waves per block
#define BPW   2     // batch elements per wave
#define L2E 1.44269504088896340736f

static __device__ __forceinline__ float exp2r(float x) { return __builtin_amdgcn_exp2f(x); }
static __device__ __forceinline__ float rcpr (float x) { return __builtin_amdgcn_rcpf(x); }

template<int CTRL>
static __device__ __forceinline__ float dpp0(float x) {
    return __int_as_float(__builtin_amdgcn_update_dpp(
        0, __float_as_int(x), CTRL, 0xf, 0xf, true));
}
// sum across 64 lanes; result valid in lane 63 (shr-tree + row broadcasts)
static __device__ __forceinline__ float wave_sum63(float x) {
    x += dpp0<0x111>(x);   // row_shr:1
    x += dpp0<0x112>(x);   // row_shr:2
    x += dpp0<0x114>(x);   // row_shr:4
    x += dpp0<0x118>(x);   // row_shr:8
    x += dpp0<0x142>(x);   // row_bcast:15
    x += dpp0<0x143>(x);   // row_bcast:31
    return x;
}
static __device__ __forceinline__ float lane63(float x) {
    return __int_as_float(__builtin_amdgcn_readlane(__float_as_int(x), 63));
}
static __device__ __forceinline__ float rdlane(float x, int l) {
    return __int_as_float(__builtin_amdgcn_readlane(__float_as_int(x), l));
}

struct CellW {
    float wi[4], wf[4], wg[4], wo[4];   // input weights (prescaled)
    float vi[4], vf[4], vg[4], vo[4];   // recurrent weights (prescaled)
    float bi[4], bf[4], bg[4], bo[4];   // biases (bih+bhh, prescaled)
    float wr[4];                        // projection row
};

static __device__ __forceinline__ void load_w(CellW& W, int lane,
        const float* __restrict__ Wih, const float* __restrict__ Whh,
        const float* __restrict__ bih, const float* __restrict__ bhh,
        const float* __restrict__ Whr) {
#pragma unroll
    for (int k = 0; k < 4; ++k) {
        int u = lane + 64 * k;
        W.wi[k] = -L2E * Wih[u];
        W.wf[k] = -L2E * Wih[256 + u];
        W.wg[k] = 2.0f * L2E * Wih[512 + u];
        W.wo[k] = -L2E * Wih[768 + u];
        W.vi[k] = -L2E * Whh[u];
        W.vf[k] = -L2E * Whh[256 + u];
        W.vg[k] = 2.0f * L2E * Whh[512 + u];
        W.vo[k] = -L2E * Whh[768 + u];
        W.bi[k] = -L2E * (bih[u] + bhh[u]);
        W.bf[k] = -L2E * (bih[256 + u] + bhh[256 + u]);
        W.bg[k] = 2.0f * L2E * (bih[512 + u] + bhh[512 + u]);
        W.bo[k] = -L2E * (bih[768 + u] + bhh[768 + u]);
        W.wr[k] = Whr[u];
    }
}

// One LSTM cell step for this lane's 4 units. x,h are wave-uniform (SGPR).
// sigma(z)=1/(1+I), I=2^(-L2E z);  tanh(z)=(G-1)/(G+1), G=2^(2 L2E z)
// i*g        = (G-1) * rcp((G+1)*(1+I))
// o*tanh(c') = (E-1) * rcp((E+1)*(1+O)),  E=2^(2 L2E c') clamped
static __device__ __forceinline__ float cell(const CellW& W, float x, float h,
                                             float (&c)[4]) {
    float s = 0.0f;
#pragma unroll
    for (int k = 0; k < 4; ++k) {
        float yi = fmaf(x, W.wi[k], fmaf(h, W.vi[k], W.bi[k]));
        float yf = fmaf(x, W.wf[k], fmaf(h, W.vf[k], W.bf[k]));
        float yg = fmaf(x, W.wg[k], fmaf(h, W.vg[k], W.bg[k]));
        float yo = fmaf(x, W.wo[k], fmaf(h, W.vo[k], W.bo[k]));
        float I = exp2r(yi), F = exp2r(yf), G = exp2r(yg), O = exp2r(yo);
        float fg = rcpr(1.0f + F);
        float ig = (G - 1.0f) * rcpr((G + 1.0f) * (1.0f + I));
        float cn = fmaf(fg, c[k], ig);
        c[k] = cn;
        float yE = fminf(cn * (2.0f * L2E), 126.0f);   // overflow guard
        float E  = exp2r(yE);
        float ot = (E - 1.0f) * rcpr((E + 1.0f) * (1.0f + O));
        s = fmaf(ot, W.wr[k], s);
    }
    return s;
}

__global__ __launch_bounds__(256, 2)
void voltage_lstm_kernel(const float* __restrict__ x,
        const float* __restrict__ Wih0, const float* __restrict__ Whh0,
        const float* __restrict__ bih0, const float* __restrict__ bhh0,
        const float* __restrict__ Whr0,
        const float* __restrict__ Wih1, const float* __restrict__ Whh1,
        const float* __restrict__ bih1, const float* __restrict__ bhh1,
        const float* __restrict__ Whr1,
        const float* __restrict__ W1, const float* __restrict__ b1p,
        const float* __restrict__ W2, const float* __restrict__ b2,
        float* __restrict__ out)
{
    __shared__ __align__(16) float h1buf[WAVES][BPW][T_LEN];

    const int lane = threadIdx.x & 63;
    const int wv   = threadIdx.x >> 6;
    const int w    = blockIdx.x * WAVES + wv;
    const int bA   = w * BPW;
    const int bB   = bA + 1;

    CellW W0c, W1c;
    load_w(W0c, lane, Wih0, Whh0, bih0, bhh0, Whr0);
    load_w(W1c, lane, Wih1, Whh1, bih1, bhh1, Whr1);

    float c0A[4] = {0.f,0.f,0.f,0.f}, c0B[4] = {0.f,0.f,0.f,0.f};
    float c1A[4] = {0.f,0.f,0.f,0.f}, c1B[4] = {0.f,0.f,0.f,0.f};

    const float* xA = x + (long)bA * T_LEN;
    const float* xB = x + (long)bB * T_LEN;
    float xcA = xA[lane];              // x chunk for t in [0,64)
    float xcB = xB[lane];

    // --- prologue: layer0 step 0 (h0=0) ---
    float h0A, h0B, h1A = 0.0f, h1B = 0.0f;
    {
        float xtA = rdlane(xcA, 0), xtB = rdlane(xcB, 0);
        float sA = wave_sum63(cell(W0c, xtA, 0.0f, c0A));
        float sB = wave_sum63(cell(W0c, xtB, 0.0f, c0B));
        h0A = lane63(sA);
        h0B = lane63(sB);
    }

    // --- main loop: iter j computes layer0 step j+1 AND layer1 step j (4
    // independent cell chains across 2 batches -> ILP hides DPP/trans latency).
    for (int j = 0; j < T_LEN - 1; ++j) {
        const int idx = j + 1;
        if ((idx & 63) == 0) {
            int tl = idx + lane;
            xcA = (tl < T_LEN) ? xA[tl] : 0.0f;
            xcB = (tl < T_LEN) ? xB[tl] : 0.0f;
        }
        float xtA = rdlane(xcA, idx & 63);
        float xtB = rdlane(xcB, idx & 63);

        float a0A = cell(W0c, xtA, h0A, c0A);
        float a0B = cell(W0c, xtB, h0B, c0B);
        float a1A = cell(W1c, h0A, h1A, c1A);
        float a1B = cell(W1c, h0B, h1B, c1B);

        a0A = wave_sum63(a0A);
        a0B = wave_sum63(a0B);
        a1A = wave_sum63(a1A);
        a1B = wave_sum63(a1B);

        if (lane == 63) {
            h1buf[wv][0][j] = a1A;
            h1buf[wv][1][j] = a1B;
        }
        h0A = lane63(a0A);  h0B = lane63(a0B);
        h1A = lane63(a1A);  h1B = lane63(a1B);
    }
    // --- epilogue: layer1 step T-1 ---
    {
        float a1A = wave_sum63(cell(W1c, h0A, h1A, c1A));
        float a1B = wave_sum63(cell(W1c, h0B, h1B, c1B));
        if (lane == 63) {
            h1buf[wv][0][T_LEN - 1] = a1A;
            h1buf[wv][1][T_LEN - 1] = a1B;
        }
    }
    __syncthreads();

    // --- head: relu(h1 @ W1^T + b1) @ W2^T + b2 for both batches ---
    const float* hA = h1buf[wv][0];
    const float* hB = h1buf[wv][1];
    const int j0 = lane;                 // rows 0..63
    const int j1 = lane + 64;            // rows 64..99 (lanes 0..35)
    const bool has1 = (j1 < 100);
    const float* r0 = W1 + j0 * T_LEN;
    const float* r1 = W1 + (has1 ? j1 : 0) * T_LEN;
    float aA0 = 0.f, aA1 = 0.f, aB0 = 0.f, aB1 = 0.f;
    for (int t = 0; t < T_LEN; t += 4) {
        float4 u0 = *(const float4*)(r0 + t);
        float4 u1 = *(const float4*)(r1 + t);
        float4 pA = *(const float4*)(hA + t);
        float4 pB = *(const float4*)(hB + t);
        aA0 = fmaf(u0.x, pA.x, aA0); aA0 = fmaf(u0.y, pA.y, aA0);
        aA0 = fmaf(u0.z, pA.z, aA0); aA0 = fmaf(u0.w, pA.w, aA0);
        aA1 = fmaf(u1.x, pA.x, aA1); aA1 = fmaf(u1.y, pA.y, aA1);
        aA1 = fmaf(u1.z, pA.z, aA1); aA1 = fmaf(u1.w, pA.w, aA1);
        aB0 = fmaf(u0.x, pB.x, aB0); aB0 = fmaf(u0.y, pB.y, aB0);
        aB0 = fmaf(u0.z, pB.z, aB0); aB0 = fmaf(u0.w, pB.w, aB0);
        aB1 = fmaf(u1.x, pB.x, aB1); aB1 = fmaf(u1.y, pB.y, aB1);
        aB1 = fmaf(u1.z, pB.z, aB1); aB1 = fmaf(u1.w, pB.w, aB1);
    }
    float bb0 = b1p[j0],   w20 = W2[j0];
    float bb1 = has1 ? b1p[j1] : 0.f;
    float w21 = has1 ? W2[j1]  : 0.f;
    float sA = fmaxf(aA0 + bb0, 0.f) * w20;
    float sB = fmaxf(aB0 + bb0, 0.f) * w20;
    if (has1) {
        sA = fmaf(fmaxf(aA1 + bb1, 0.f), w21, sA);
        sB = fmaf(fmaxf(aB1 + bb1, 0.f), w21, sB);
    }
    sA = wave_sum63(sA);
    sB = wave_sum63(sB);
    if (lane == 63) {
        float bias2 = b2[0];
        out[bA] = sA + bias2;
        out[bB] = sB + bias2;
    }
}

extern "C" void kernel_launch(void* const* d_in, const int* in_sizes, int n_in,
                              void* d_out, int out_size, void* d_ws, size_t ws_size,
                              hipStream_t stream) {
    (void)in_sizes; (void)n_in; (void)d_ws; (void)ws_size; (void)out_size;
    const float* x    = (const float*)d_in[0];
    const float* Wih0 = (const float*)d_in[1];
    const float* Whh0 = (const float*)d_in[2];
    const float* bih0 = (const float*)d_in[3];
    const float* bhh0 = (const float*)d_in[4];
    const float* Whr0 = (const float*)d_in[5];
    const float* Wih1 = (const float*)d_in[6];
    const float* Whh1 = (const float*)d_in[7];
    const float* bih1 = (const float*)d_in[8];
    const float* bhh1 = (const float*)d_in[9];
    const float* Whr1 = (const float*)d_in[10];
    const float* W1   = (const float*)d_in[11];
    const float* b1   = (const float*)d_in[12];
    const float* W2   = (const float*)d_in[13];
    const float* b2   = (const float*)d_in[14];
    float* outp = (float*)d_out;

    dim3 grid(16384 / (WAVES * BPW)), block(256);
    voltage_lstm_kernel<<<grid, block, 0, stream>>>(
        x, Wih0, Whh0, bih0, bhh0, Whr0,
        Wih1, Whh1, bih1, bhh1, Whr1,
        W1, b1, W2, b2, outp);
}

// Round 5
// 6616.962 us; speedup vs baseline: 2.1336x; 1.2818x over previous
//
#include <hip/hip_runtime.h>

// voltageNN: 2-layer LSTM (H=256, P=1, in=1), T=1000, B=16384, + MLP head.
// One wave per 2 batch elements; lane owns units u = lane + 64k (k=0..3) for
// both layers, processed as PACKED pairs k={2p,2p+1} on float2 (v_pk_*_f32).
// Recurrent scalars via readlane (SGPR); reduction via DPP shr-tree (no LDS).
// Trans budget: 6/unit-step (5 exp2 + 1 merged rcp) via common-denominator:
//   sigmoid(z)=1/(1+I), I=2^(-L2E z); tanh(z)=(G-1)/(G+1), G=2^(2 L2E z)
//   cn = [u*c + (G-1)(1+F)] / [(1+F)*u],  u=(G+1)(1+I)   (one rcp per 2 units)
//   o*tanh(cn) = (E-1) / [(E+1)(1+O)],    E=2^(2 L2E cn) (one rcp per 2 units)

#define T_LEN 1000
#define WAVES 4     // waves per block
#define BPW   2     // batch elements per wave
#define L2E 1.44269504088896340736f

typedef float v2f __attribute__((ext_vector_type(2)));

static __device__ __forceinline__ float exp2r(float x) { return __builtin_amdgcn_exp2f(x); }
static __device__ __forceinline__ float rcpr (float x) { return __builtin_amdgcn_rcpf(x); }
static __device__ __forceinline__ v2f fma2(v2f a, v2f b, v2f c) {
    return __builtin_elementwise_fma(a, b, c);
}
static __device__ __forceinline__ v2f splat2(float s) { v2f r; r.x = s; r.y = s; return r; }
static __device__ __forceinline__ v2f swap2(v2f a) { return __builtin_shufflevector(a, a, 1, 0); }

template<int CTRL>
static __device__ __forceinline__ float dpp0(float x) {
    return __int_as_float(__builtin_amdgcn_update_dpp(
        0, __float_as_int(x), CTRL, 0xf, 0xf, true));
}
// sum across 64 lanes; result valid in lane 63
static __device__ __forceinline__ float wave_sum63(float x) {
    x += dpp0<0x111>(x);   // row_shr:1
    x += dpp0<0x112>(x);   // row_shr:2
    x += dpp0<0x114>(x);   // row_shr:4
    x += dpp0<0x118>(x);   // row_shr:8
    x += dpp0<0x142>(x);   // row_bcast:15
    x += dpp0<0x143>(x);   // row_bcast:31
    return x;
}
static __device__ __forceinline__ float lane63(float x) {
    return __int_as_float(__builtin_amdgcn_readlane(__float_as_int(x), 63));
}
static __device__ __forceinline__ float rdlane(float x, int l) {
    return __int_as_float(__builtin_amdgcn_readlane(__float_as_int(x), l));
}

struct CellW {
    v2f wi[2], wf[2], wg[2], wo[2];   // input weights (prescaled), pair p = units {lane+128p, lane+128p+64}
    v2f vi[2], vf[2], vg[2], vo[2];   // recurrent weights (prescaled)
    v2f bi[2], bf[2], bg[2], bo[2];   // biases (bih+bhh, prescaled)
    v2f wr[2];                        // projection row
};

static __device__ __forceinline__ void load_w(CellW& W, int lane,
        const float* __restrict__ Wih, const float* __restrict__ Whh,
        const float* __restrict__ bih, const float* __restrict__ bhh,
        const float* __restrict__ Whr) {
#pragma unroll
    for (int p = 0; p < 2; ++p) {
        int ua = lane + 128 * p;
        int ub = ua + 64;
        v2f t;
        t.x = Wih[ua];        t.y = Wih[ub];        W.wi[p] = t * (-L2E);
        t.x = Wih[256 + ua];  t.y = Wih[256 + ub];  W.wf[p] = t * (-L2E);
        t.x = Wih[512 + ua];  t.y = Wih[512 + ub];  W.wg[p] = t * (2.0f * L2E);
        t.x = Wih[768 + ua];  t.y = Wih[768 + ub];  W.wo[p] = t * (-L2E);
        t.x = Whh[ua];        t.y = Whh[ub];        W.vi[p] = t * (-L2E);
        t.x = Whh[256 + ua];  t.y = Whh[256 + ub];  W.vf[p] = t * (-L2E);
        t.x = Whh[512 + ua];  t.y = Whh[512 + ub];  W.vg[p] = t * (2.0f * L2E);
        t.x = Whh[768 + ua];  t.y = Whh[768 + ub];  W.vo[p] = t * (-L2E);
        t.x = bih[ua] + bhh[ua];
        t.y = bih[ub] + bhh[ub];                    W.bi[p] = t * (-L2E);
        t.x = bih[256 + ua] + bhh[256 + ua];
        t.y = bih[256 + ub] + bhh[256 + ub];        W.bf[p] = t * (-L2E);
        t.x = bih[512 + ua] + bhh[512 + ua];
        t.y = bih[512 + ub] + bhh[512 + ub];        W.bg[p] = t * (2.0f * L2E);
        t.x = bih[768 + ua] + bhh[768 + ua];
        t.y = bih[768 + ub] + bhh[768 + ub];        W.bo[p] = t * (-L2E);
        t.x = Whr[ua];        t.y = Whr[ub];        W.wr[p] = t;
    }
}

// One LSTM cell step for this lane's 4 units (2 packed pairs). x,h wave-uniform.
static __device__ __forceinline__ float cell(const CellW& W, float x, float h,
                                             v2f (&c)[2]) {
    float s = 0.0f;
    const v2f xs = splat2(x);
    const v2f hs = splat2(h);
#pragma unroll
    for (int p = 0; p < 2; ++p) {
        v2f yi = fma2(xs, W.wi[p], fma2(hs, W.vi[p], W.bi[p]));
        v2f yf = fma2(xs, W.wf[p], fma2(hs, W.vf[p], W.bf[p]));
        v2f yg = fma2(xs, W.wg[p], fma2(hs, W.vg[p], W.bg[p]));
        v2f yo = fma2(xs, W.wo[p], fma2(hs, W.vo[p], W.bo[p]));
        v2f I, F, G, O;
        I.x = exp2r(yi.x); I.y = exp2r(yi.y);
        F.x = exp2r(yf.x); F.y = exp2r(yf.y);
        G.x = exp2r(yg.x); G.y = exp2r(yg.y);
        O.x = exp2r(yo.x); O.y = exp2r(yo.y);
        v2f w1  = F + 1.0f;
        v2f u   = (G + 1.0f) * (I + 1.0f);
        v2f num = fma2(u, c[p], (G - 1.0f) * w1);
        v2f D   = w1 * u;                          // per-unit denominator
        float rP = rcpr(D.x * D.y);                // merged rcp (pair)
        v2f cn  = (num * swap2(D)) * splat2(rP);
        c[p] = cn;
        v2f yE = cn * splat2(2.0f * L2E);
        v2f E;
        E.x = exp2r(fminf(yE.x, 40.0f));           // overflow guard (inert in practice)
        E.y = exp2r(fminf(yE.y, 40.0f));
        v2f d = (E + 1.0f) * (O + 1.0f);
        float rQ = rcpr(d.x * d.y);                // merged rcp (pair)
        v2f q = ((E - 1.0f) * W.wr[p]) * swap2(d);
        s = fmaf(q.x + q.y, rQ, s);
    }
    return s;
}

__global__ __launch_bounds__(256, 2)
void voltage_lstm_kernel(const float* __restrict__ x,
        const float* __restrict__ Wih0, const float* __restrict__ Whh0,
        const float* __restrict__ bih0, const float* __restrict__ bhh0,
        const float* __restrict__ Whr0,
        const float* __restrict__ Wih1, const float* __restrict__ Whh1,
        const float* __restrict__ bih1, const float* __restrict__ bhh1,
        const float* __restrict__ Whr1,
        const float* __restrict__ W1, const float* __restrict__ b1p,
        const float* __restrict__ W2, const float* __restrict__ b2,
        float* __restrict__ out)
{
    __shared__ __align__(16) float h1buf[WAVES][BPW][T_LEN];

    const int lane = threadIdx.x & 63;
    const int wv   = threadIdx.x >> 6;
    const int w    = blockIdx.x * WAVES + wv;
    const int bA   = w * BPW;
    const int bB   = bA + 1;

    CellW W0c, W1c;
    load_w(W0c, lane, Wih0, Whh0, bih0, bhh0, Whr0);
    load_w(W1c, lane, Wih1, Whh1, bih1, bhh1, Whr1);

    v2f c0A[2], c0B[2], c1A[2], c1B[2];
#pragma unroll
    for (int p = 0; p < 2; ++p) {
        c0A[p] = splat2(0.f); c0B[p] = splat2(0.f);
        c1A[p] = splat2(0.f); c1B[p] = splat2(0.f);
    }

    const float* xA = x + (long)bA * T_LEN;
    const float* xB = x + (long)bB * T_LEN;
    float xcA = xA[lane];              // x chunk for t in [0,64)
    float xcB = xB[lane];

    // --- prologue: layer0 step 0 (h0=0) ---
    float h0A, h0B, h1A = 0.0f, h1B = 0.0f;
    {
        float xtA = rdlane(xcA, 0), xtB = rdlane(xcB, 0);
        float sA = wave_sum63(cell(W0c, xtA, 0.0f, c0A));
        float sB = wave_sum63(cell(W0c, xtB, 0.0f, c0B));
        h0A = lane63(sA);
        h0B = lane63(sB);
    }

    // --- main loop: iter j computes layer0 step j+1 AND layer1 step j
    // (4 independent cell chains across 2 batches -> ILP).
    for (int j = 0; j < T_LEN - 1; ++j) {
        const int idx = j + 1;
        if ((idx & 63) == 0) {
            int tl = idx + lane;
            xcA = (tl < T_LEN) ? xA[tl] : 0.0f;
            xcB = (tl < T_LEN) ? xB[tl] : 0.0f;
        }
        float xtA = rdlane(xcA, idx & 63);
        float xtB = rdlane(xcB, idx & 63);

        float a0A = cell(W0c, xtA, h0A, c0A);
        float a0B = cell(W0c, xtB, h0B, c0B);
        float a1A = cell(W1c, h0A, h1A, c1A);
        float a1B = cell(W1c, h0B, h1B, c1B);

        a0A = wave_sum63(a0A);
        a0B = wave_sum63(a0B);
        a1A = wave_sum63(a1A);
        a1B = wave_sum63(a1B);

        if (lane == 63) {
            h1buf[wv][0][j] = a1A;
            h1buf[wv][1][j] = a1B;
        }
        h0A = lane63(a0A);  h0B = lane63(a0B);
        h1A = lane63(a1A);  h1B = lane63(a1B);
    }
    // --- epilogue: layer1 step T-1 ---
    {
        float a1A = wave_sum63(cell(W1c, h0A, h1A, c1A));
        float a1B = wave_sum63(cell(W1c, h0B, h1B, c1B));
        if (lane == 63) {
            h1buf[wv][0][T_LEN - 1] = a1A;
            h1buf[wv][1][T_LEN - 1] = a1B;
        }
    }
    __syncthreads();

    // --- head: relu(h1 @ W1^T + b1) @ W2^T + b2 for both batches ---
    const float* hA = h1buf[wv][0];
    const float* hB = h1buf[wv][1];
    const int j0 = lane;                 // rows 0..63
    const int j1 = lane + 64;            // rows 64..99 (lanes 0..35)
    const bool has1 = (j1 < 100);
    const float* r0 = W1 + j0 * T_LEN;
    const float* r1 = W1 + (has1 ? j1 : 0) * T_LEN;
    float aA0 = 0.f, aA1 = 0.f, aB0 = 0.f, aB1 = 0.f;
    for (int t = 0; t < T_LEN; t += 4) {
        float4 u0 = *(const float4*)(r0 + t);
        float4 u1 = *(const float4*)(r1 + t);
        float4 pA = *(const float4*)(hA + t);
        float4 pB = *(const float4*)(hB + t);
        aA0 = fmaf(u0.x, pA.x, aA0); aA0 = fmaf(u0.y, pA.y, aA0);
        aA0 = fmaf(u0.z, pA.z, aA0); aA0 = fmaf(u0.w, pA.w, aA0);
        aA1 = fmaf(u1.x, pA.x, aA1); aA1 = fmaf(u1.y, pA.y, aA1);
        aA1 = fmaf(u1.z, pA.z, aA1); aA1 = fmaf(u1.w, pA.w, aA1);
        aB0 = fmaf(u0.x, pB.x, aB0); aB0 = fmaf(u0.y, pB.y, aB0);
        aB0 = fmaf(u0.z, pB.z, aB0); aB0 = fmaf(u0.w, pB.w, aB0);
        aB1 = fmaf(u1.x, pB.x, aB1); aB1 = fmaf(u1.y, pB.y, aB1);
        aB1 = fmaf(u1.z, pB.z, aB1); aB1 = fmaf(u1.w, pB.w, aB1);
    }
    float bb0 = b1p[j0],   w20 = W2[j0];
    float bb1 = has1 ? b1p[j1] : 0.f;
    float w21 = has1 ? W2[j1]  : 0.f;
    float sA = fmaxf(aA0 + bb0, 0.f) * w20;
    float sB = fmaxf(aB0 + bb0, 0.f) * w20;
    if (has1) {
        sA = fmaf(fmaxf(aA1 + bb1, 0.f), w21, sA);
        sB = fmaf(fmaxf(aB1 + bb1, 0.f), w21, sB);
    }
    sA = wave_sum63(sA);
    sB = wave_sum63(sB);
    if (lane == 63) {
        float bias2 = b2[0];
        out[bA] = sA + bias2;
        out[bB] = sB + bias2;
    }
}

extern "C" void kernel_launch(void* const* d_in, const int* in_sizes, int n_in,
                              void* d_out, int out_size, void* d_ws, size_t ws_size,
                              hipStream_t stream) {
    (void)in_sizes; (void)n_in; (void)d_ws; (void)ws_size; (void)out_size;
    const float* x    = (const float*)d_in[0];
    const float* Wih0 = (const float*)d_in[1];
    const float* Whh0 = (const float*)d_in[2];
    const float* bih0 = (const float*)d_in[3];
    const float* bhh0 = (const float*)d_in[4];
    const float* Whr0 = (const float*)d_in[5];
    const float* Wih1 = (const float*)d_in[6];
    const float* Whh1 = (const float*)d_in[7];
    const float* bih1 = (const float*)d_in[8];
    const float* bhh1 = (const float*)d_in[9];
    const float* Whr1 = (const float*)d_in[10];
    const float* W1   = (const float*)d_in[11];
    const float* b1   = (const float*)d_in[12];
    const float* W2   = (const float*)d_in[13];
    const float* b2   = (const float*)d_in[14];
    float* outp = (float*)d_out;

    dim3 grid(16384 / (WAVES * BPW)), block(256);
    voltage_lstm_kernel<<<grid, block, 0, stream>>>(
        x, Wih0, Whh0, bih0, bhh0, Whr0,
        Wih1, Whh1, bih1, bhh1, Whr1,
        W1, b1, W2, b2, outp);
}